// Round 2
// baseline (3326.560 us; speedup 1.0000x reference)
//
#include <hip/hip_runtime.h>
#include <math.h>

#define D 1024
#define V 16384
#define NROWS 8192

// ---------------- row L2-norm (rsqrt of sum of squares) ----------------
__global__ __launch_bounds__(256) void rownorm_kernel(const float* __restrict__ M,
                                                      float* __restrict__ R, int nrows) {
    int tid = threadIdx.x;
    int row = blockIdx.x * 4 + (tid >> 6);
    int lane = tid & 63;
    if (row >= nrows) return;
    const float4* p = (const float4*)(M + (size_t)row * D);
    float ss = 0.f;
#pragma unroll
    for (int i = 0; i < 4; ++i) {
        float4 v = p[lane + 64 * i];
        ss += v.x * v.x + v.y * v.y + v.z * v.z + v.w * v.w;
    }
#pragma unroll
    for (int m = 32; m >= 1; m >>= 1) ss += __shfl_xor(ss, m, 64);
    if (lane == 0) R[row] = rsqrtf(fmaxf(ss, 1e-12f));
}

// ---------------- zero the packed argmax array ----------------
__global__ __launch_bounds__(256) void zero_kernel(unsigned long long* __restrict__ p, int n) {
    int i = blockIdx.x * 256 + threadIdx.x;
    if (i < n) p[i] = 0ull;
}

__device__ __forceinline__ unsigned int sortable_key(float v) {
    unsigned int b = __float_as_uint(v);
    return (b & 0x80000000u) ? ~b : (b | 0x80000000u);
}

// ---------------- sim GEMM (raw dot) + fused argmax via packed atomicMax ----------------
__global__ __launch_bounds__(256) void gemm1_kernel(const float* __restrict__ X,
                                                    const float* __restrict__ W,
                                                    const float* __restrict__ RQ,
                                                    const float* __restrict__ RK,
                                                    unsigned long long* __restrict__ packed) {
    const int AP = 132;  // padded pitch: breaks power-of-2 bank strides
    __shared__ __align__(16) float As[16 * AP];
    __shared__ __align__(16) float Bs[16 * AP];
    __shared__ float redV[128 * 16];
    __shared__ int   redI[128 * 16];

    int tid = threadIdx.x;
    int tx = tid & 15, ty = tid >> 4;
    int rowBase = blockIdx.y * 128;
    int cwBase  = blockIdx.x * 128;

    float acc[8][8];
#pragma unroll
    for (int r = 0; r < 8; ++r)
#pragma unroll
        for (int c = 0; c < 8; ++c) acc[r][c] = 0.f;

    for (int kc = 0; kc < D; kc += 16) {
#pragma unroll
        for (int i = 0; i < 2; ++i) {
            int f = tid + i * 256;
            int row = f >> 2;
            int d4 = (f & 3) * 4;
            float4 a = *(const float4*)(X + (size_t)(rowBase + row) * D + kc + d4);
            As[(d4 + 0) * AP + row] = a.x;
            As[(d4 + 1) * AP + row] = a.y;
            As[(d4 + 2) * AP + row] = a.z;
            As[(d4 + 3) * AP + row] = a.w;
            float4 b = *(const float4*)(W + (size_t)(cwBase + row) * D + kc + d4);
            Bs[(d4 + 0) * AP + row] = b.x;
            Bs[(d4 + 1) * AP + row] = b.y;
            Bs[(d4 + 2) * AP + row] = b.z;
            Bs[(d4 + 3) * AP + row] = b.w;
        }
        __syncthreads();
#pragma unroll
        for (int d = 0; d < 16; ++d) {
            float4 a0 = *(const float4*)(As + d * AP + ty * 4);
            float4 a1 = *(const float4*)(As + d * AP + 64 + ty * 4);
            float4 b0 = *(const float4*)(Bs + d * AP + tx * 4);
            float4 b1 = *(const float4*)(Bs + d * AP + 64 + tx * 4);
            float ar[8] = {a0.x, a0.y, a0.z, a0.w, a1.x, a1.y, a1.z, a1.w};
            float br[8] = {b0.x, b0.y, b0.z, b0.w, b1.x, b1.y, b1.z, b1.w};
#pragma unroll
            for (int r = 0; r < 8; ++r)
#pragma unroll
                for (int c = 0; c < 8; ++c)
                    acc[r][c] = fmaf(ar[r], br[c], acc[r][c]);
        }
        __syncthreads();
    }

    // epilogue: apply deferred norms, per-thread argmax over its 8 cols
    float rq[8], rk[8];
#pragma unroll
    for (int r = 0; r < 4; ++r) {
        rq[r]     = RQ[rowBase + ty * 4 + r];
        rq[r + 4] = RQ[rowBase + 64 + ty * 4 + r];
    }
#pragma unroll
    for (int c = 0; c < 4; ++c) {
        rk[c]     = RK[cwBase + tx * 4 + c];
        rk[c + 4] = RK[cwBase + 64 + tx * 4 + c];
    }
#pragma unroll
    for (int r = 0; r < 8; ++r) {
        float best = -INFINITY;
        int bi = 0x7fffffff;
#pragma unroll
        for (int c = 0; c < 8; ++c) {
            float v = acc[r][c] * rq[r] * rk[c];
            int gcol = cwBase + ((c < 4) ? (tx * 4 + c) : (64 + tx * 4 + c - 4));
            if (v > best || (v == best && gcol < bi)) { best = v; bi = gcol; }
        }
        int lrow = (r < 4) ? (ty * 4 + r) : (64 + ty * 4 + r - 4);
        redV[lrow * 16 + tx] = best;
        redI[lrow * 16 + tx] = bi;
    }
    __syncthreads();
    if (tid < 128) {
        float best = -INFINITY;
        int bi = 0x7fffffff;
#pragma unroll
        for (int t = 0; t < 16; ++t) {
            float v = redV[tid * 16 + t];
            int i = redI[tid * 16 + t];
            if (v > best || (v == best && i < bi)) { best = v; bi = i; }
        }
        // pack: high 32 = sortable sim key, low 32 = ~idx (tie -> smaller idx wins)
        unsigned long long pk = ((unsigned long long)sortable_key(best) << 32) |
                                (unsigned long long)(~(unsigned int)bi);
        atomicMax(packed + (rowBase + tid), pk);
    }
}

// ---------------- unpack argmax results ----------------
__global__ __launch_bounds__(256) void finalize_kernel(const unsigned long long* __restrict__ packed,
                                                       float* __restrict__ outIdx,
                                                       float* __restrict__ outSim,
                                                       int* __restrict__ idxArr) {
    int row = blockIdx.x * 256 + threadIdx.x;
    if (row >= NROWS) return;
    unsigned long long p = packed[row];
    unsigned int key = (unsigned int)(p >> 32);
    unsigned int b = (key & 0x80000000u) ? (key & 0x7FFFFFFFu) : ~key;
    int idx = (int)(~(unsigned int)(p & 0xFFFFFFFFull));
    outIdx[row] = (float)idx;
    outSim[row] = __uint_as_float(b);
    idxArr[row] = idx;
}

// ---------------- per-row LN stats (mean, rstd) of e = (z-x)+x ----------------
__global__ __launch_bounds__(256) void ln_stats_kernel(const float* __restrict__ X,
                                                       const float* __restrict__ W,
                                                       const int* __restrict__ idxArr,
                                                       float* __restrict__ MU,
                                                       float* __restrict__ RS) {
    __shared__ float red[8];
    int row = blockIdx.x;
    int tid = threadIdx.x;
    int idx = idxArr[row];
    float4 z  = *((const float4*)(W + (size_t)idx * D) + tid);
    float4 xv = *((const float4*)(X + (size_t)row * D) + tid);
    float4 e;
    e.x = (z.x - xv.x) + xv.x;
    e.y = (z.y - xv.y) + xv.y;
    e.z = (z.z - xv.z) + xv.z;
    e.w = (z.w - xv.w) + xv.w;
    float s  = e.x + e.y + e.z + e.w;
    float s2 = e.x * e.x + e.y * e.y + e.z * e.z + e.w * e.w;
#pragma unroll
    for (int m = 32; m >= 1; m >>= 1) {
        s  += __shfl_xor(s, m, 64);
        s2 += __shfl_xor(s2, m, 64);
    }
    int wave = tid >> 6, lane = tid & 63;
    if (lane == 0) { red[wave] = s; red[4 + wave] = s2; }
    __syncthreads();
    if (tid == 0) {
        s  = red[0] + red[1] + red[2] + red[3];
        s2 = red[4] + red[5] + red[6] + red[7];
        float mean = s * (1.f / D);
        float var  = s2 * (1.f / D) - mean * mean;
        MU[row] = mean;
        RS[row] = rsqrtf(var + 1e-6f);
    }
}

// ---------------- projection GEMM with fused gather+STE+LN on A-staging ----------------
__global__ __launch_bounds__(256) void gemm2_kernel(const float* __restrict__ X,
                                                    const float* __restrict__ W,
                                                    const int* __restrict__ idxArr,
                                                    const float* __restrict__ MU,
                                                    const float* __restrict__ RS,
                                                    const float* __restrict__ gamma,
                                                    const float* __restrict__ beta,
                                                    const float* __restrict__ B,
                                                    float* __restrict__ Out) {
    const int AP = 132;
    __shared__ __align__(16) float As[16 * AP];
    __shared__ __align__(16) float Bs[16 * AP];
    int tid = threadIdx.x;
    int tx = tid & 15, ty = tid >> 4;
    int rowBase = blockIdx.y * 128;
    int nBase   = blockIdx.x * 128;
    float acc[8][8];
#pragma unroll
    for (int r = 0; r < 8; ++r)
#pragma unroll
        for (int c = 0; c < 8; ++c) acc[r][c] = 0.f;

    for (int kc = 0; kc < D; kc += 16) {
#pragma unroll
        for (int i = 0; i < 2; ++i) {
            int f = tid + i * 256;
            int row = f >> 2;
            int d4 = (f & 3) * 4;
            int grow = rowBase + row;
            int col = kc + d4;
            // fused: e_ln[grow][col..col+3] computed on the fly
            int idx = idxArr[grow];
            float4 z  = *(const float4*)(W + (size_t)idx * D + col);
            float4 xv = *(const float4*)(X + (size_t)grow * D + col);
            float4 g  = *(const float4*)(gamma + col);
            float4 bb = *(const float4*)(beta + col);
            float mu_ = MU[grow];
            float rs_ = RS[grow];
            float4 a;
            a.x = (((z.x - xv.x) + xv.x) - mu_) * rs_ * g.x + bb.x;
            a.y = (((z.y - xv.y) + xv.y) - mu_) * rs_ * g.y + bb.y;
            a.z = (((z.z - xv.z) + xv.z) - mu_) * rs_ * g.z + bb.z;
            a.w = (((z.w - xv.w) + xv.w) - mu_) * rs_ * g.w + bb.w;
            As[(d4 + 0) * AP + row] = a.x;
            As[(d4 + 1) * AP + row] = a.y;
            As[(d4 + 2) * AP + row] = a.z;
            As[(d4 + 3) * AP + row] = a.w;
            int n4 = (f & 31) * 4;
            int d  = f >> 5;
            float4 b = *(const float4*)(B + (size_t)(kc + d) * D + nBase + n4);
            *(float4*)(Bs + d * AP + n4) = b;
        }
        __syncthreads();
#pragma unroll
        for (int d = 0; d < 16; ++d) {
            float4 a0 = *(const float4*)(As + d * AP + ty * 4);
            float4 a1 = *(const float4*)(As + d * AP + 64 + ty * 4);
            float4 b0 = *(const float4*)(Bs + d * AP + tx * 4);
            float4 b1 = *(const float4*)(Bs + d * AP + 64 + tx * 4);
            float ar[8] = {a0.x, a0.y, a0.z, a0.w, a1.x, a1.y, a1.z, a1.w};
            float br[8] = {b0.x, b0.y, b0.z, b0.w, b1.x, b1.y, b1.z, b1.w};
#pragma unroll
            for (int r = 0; r < 8; ++r)
#pragma unroll
                for (int c = 0; c < 8; ++c)
                    acc[r][c] = fmaf(ar[r], br[c], acc[r][c]);
        }
        __syncthreads();
    }
#pragma unroll
    for (int r = 0; r < 8; ++r) {
        int lrow = (r < 4) ? (ty * 4 + r) : (64 + ty * 4 + r - 4);
        float4 o0 = {acc[r][0], acc[r][1], acc[r][2], acc[r][3]};
        float4 o1 = {acc[r][4], acc[r][5], acc[r][6], acc[r][7]};
        *(float4*)(Out + (size_t)(rowBase + lrow) * D + nBase + tx * 4) = o0;
        *(float4*)(Out + (size_t)(rowBase + lrow) * D + nBase + 64 + tx * 4) = o1;
    }
}

extern "C" void kernel_launch(void* const* d_in, const int* in_sizes, int n_in,
                              void* d_out, int out_size, void* d_ws, size_t ws_size,
                              hipStream_t stream) {
    const float* X     = (const float*)d_in[0];  // [8192,1024]
    const float* W     = (const float*)d_in[1];  // [16384,1024]
    const float* gamma = (const float*)d_in[2];  // [1024]
    const float* beta  = (const float*)d_in[3];  // [1024]
    const float* OW    = (const float*)d_in[4];  // [1024,1024]

    float* out    = (float*)d_out;
    float* outIdx = out;               // word_idx as float values
    float* outSim = out + NROWS;       // word_sim
    float* outO   = out + 2 * NROWS;   // projection output

    // workspace layout — 256 KB total (ws is re-poisoned 0xAA each launch)
    unsigned long long* packed = (unsigned long long*)d_ws;  // 8192 u64 (8B-aligned base)
    float* RK     = (float*)(packed + NROWS);                // 16384 f
    float* RQ     = RK + V;                                  // 8192 f
    float* MU     = RQ + NROWS;                              // 8192 f
    float* RS     = MU + NROWS;                              // 8192 f
    int*   idxArr = (int*)(RS + NROWS);                      // 8192 i

    hipLaunchKernelGGL(rownorm_kernel, dim3(V / 4), dim3(256), 0, stream, W, RK, V);
    hipLaunchKernelGGL(rownorm_kernel, dim3(NROWS / 4), dim3(256), 0, stream, X, RQ, NROWS);
    hipLaunchKernelGGL(zero_kernel, dim3(NROWS / 256), dim3(256), 0, stream, packed, NROWS);
    hipLaunchKernelGGL(gemm1_kernel, dim3(128, 64), dim3(256), 0, stream, X, W, RQ, RK, packed);
    hipLaunchKernelGGL(finalize_kernel, dim3(NROWS / 256), dim3(256), 0, stream, packed, outIdx, outSim, idxArr);
    hipLaunchKernelGGL(ln_stats_kernel, dim3(NROWS), dim3(256), 0, stream, X, W, idxArr, MU, RS);
    hipLaunchKernelGGL(gemm2_kernel, dim3(8, 64), dim3(256), 0, stream, X, W, idxArr, MU, RS, gamma, beta, OW, outO);
}

// Round 3
// 1272.373 us; speedup vs baseline: 2.6145x; 2.6145x over previous
//
#include <hip/hip_runtime.h>
#include <math.h>

#define D 1024
#define V 16384
#define NROWS 8192

typedef __bf16 bf16_t;
typedef bf16_t bf16x8 __attribute__((ext_vector_type(8)));
typedef float f32x4 __attribute__((ext_vector_type(4)));

__device__ __forceinline__ unsigned int sortable_key(float v) {
    unsigned int b = __float_as_uint(v);
    return (b & 0x80000000u) ? ~b : (b | 0x80000000u);
}

// ---------------- row L2-norm (rsqrt of sum of squares) ----------------
__global__ __launch_bounds__(256) void rownorm_kernel(const float* __restrict__ M,
                                                      float* __restrict__ R, int nrows) {
    int tid = threadIdx.x;
    int row = blockIdx.x * 4 + (tid >> 6);
    int lane = tid & 63;
    if (row >= nrows) return;
    const float4* p = (const float4*)(M + (size_t)row * D);
    float ss = 0.f;
#pragma unroll
    for (int i = 0; i < 4; ++i) {
        float4 v = p[lane + 64 * i];
        ss += v.x * v.x + v.y * v.y + v.z * v.z + v.w * v.w;
    }
#pragma unroll
    for (int m = 32; m >= 1; m >>= 1) ss += __shfl_xor(ss, m, 64);
    if (lane == 0) R[row] = rsqrtf(fmaxf(ss, 1e-12f));
}

// ---------------- zero the packed argmax array ----------------
__global__ __launch_bounds__(256) void zero_kernel(unsigned long long* __restrict__ p, int n) {
    int i = blockIdx.x * 256 + threadIdx.x;
    if (i < n) p[i] = 0ull;
}

// ---------------- sim GEMM via bf16 double-double MFMA + fused argmax ----------------
// sim(row, col) = dot(X[row], W[col]); x = hi + lo (two bf16 via truncation split);
// dot = hh + ll + hl + lh (4 MFMA passes) reconstructs ~fp32 precision.
// Deferred norms: argmax over col of dot*rk[col] (rq row-constant>0, applied in finalize).
__global__ __launch_bounds__(256) void gemm1_kernel(const float* __restrict__ X,
                                                    const float* __restrict__ W,
                                                    const float* __restrict__ RK,
                                                    unsigned long long* __restrict__ packed) {
    // fragment-ordered LDS: [m_tile][lane][8 bf16] -> lane*16B contiguous, conflict-free reads
    __shared__ ushort Ah[8][64][8];
    __shared__ ushort Al[8][64][8];
    __shared__ ushort Bh[8][64][8];
    __shared__ ushort Bl[8][64][8];
    __shared__ unsigned long long red[128][2];

    const int tid = threadIdx.x;
    const int l = tid & 63;
    const int wave = tid >> 6;
    const int wy = wave >> 1, wx = wave & 1;   // 2x2 wave tiling: 64x64 per wave
    const int rowBase = blockIdx.y * 128;
    const int cwBase  = blockIdx.x * 128;

    f32x4 acc[4][4];
#pragma unroll
    for (int mt = 0; mt < 4; ++mt)
#pragma unroll
        for (int nt = 0; nt < 4; ++nt) acc[mt][nt] = (f32x4)0.f;

    const float4* Xb = (const float4*)(X + (size_t)rowBase * D);
    const float4* Wb = (const float4*)(W + (size_t)cwBase * D);

    float4 pa[4], pb[4];
#pragma unroll
    for (int i = 0; i < 4; ++i) {
        int f = i * 256 + tid;
        int row = f >> 3, kq = f & 7;
        pa[i] = Xb[row * (D / 4) + kq];
        pb[i] = Wb[row * (D / 4) + kq];
    }

    for (int kc = 0; kc < 32; ++kc) {
        __syncthreads();
#pragma unroll
        for (int i = 0; i < 4; ++i) {
            int f = i * 256 + tid;
            int row = f >> 3, kq = f & 7;
            int mt = row >> 4;
            int lf = (row & 15) | ((kq >> 1) << 4);
            int j0 = (kq & 1) * 4;
            {
                float4 v = pa[i];
                unsigned int u0 = __float_as_uint(v.x), u1 = __float_as_uint(v.y);
                unsigned int u2 = __float_as_uint(v.z), u3 = __float_as_uint(v.w);
                float l0 = v.x - __uint_as_float(u0 & 0xFFFF0000u);
                float l1 = v.y - __uint_as_float(u1 & 0xFFFF0000u);
                float l2 = v.z - __uint_as_float(u2 & 0xFFFF0000u);
                float l3 = v.w - __uint_as_float(u3 & 0xFFFF0000u);
                uint2 hw = {(u0 >> 16) | (u1 & 0xFFFF0000u), (u2 >> 16) | (u3 & 0xFFFF0000u)};
                uint2 lw = {(__float_as_uint(l0) >> 16) | (__float_as_uint(l1) & 0xFFFF0000u),
                            (__float_as_uint(l2) >> 16) | (__float_as_uint(l3) & 0xFFFF0000u)};
                *(uint2*)&Ah[mt][lf][j0] = hw;
                *(uint2*)&Al[mt][lf][j0] = lw;
            }
            {
                float4 v = pb[i];
                unsigned int u0 = __float_as_uint(v.x), u1 = __float_as_uint(v.y);
                unsigned int u2 = __float_as_uint(v.z), u3 = __float_as_uint(v.w);
                float l0 = v.x - __uint_as_float(u0 & 0xFFFF0000u);
                float l1 = v.y - __uint_as_float(u1 & 0xFFFF0000u);
                float l2 = v.z - __uint_as_float(u2 & 0xFFFF0000u);
                float l3 = v.w - __uint_as_float(u3 & 0xFFFF0000u);
                uint2 hw = {(u0 >> 16) | (u1 & 0xFFFF0000u), (u2 >> 16) | (u3 & 0xFFFF0000u)};
                uint2 lw = {(__float_as_uint(l0) >> 16) | (__float_as_uint(l1) & 0xFFFF0000u),
                            (__float_as_uint(l2) >> 16) | (__float_as_uint(l3) & 0xFFFF0000u)};
                *(uint2*)&Bh[mt][lf][j0] = hw;
                *(uint2*)&Bl[mt][lf][j0] = lw;
            }
        }
        __syncthreads();
        if (kc < 31) {
#pragma unroll
            for (int i = 0; i < 4; ++i) {
                int f = i * 256 + tid;
                int row = f >> 3, kq = f & 7;
                pa[i] = Xb[row * (D / 4) + (kc + 1) * 8 + kq];
                pb[i] = Wb[row * (D / 4) + (kc + 1) * 8 + kq];
            }
        }
        bf16x8 ah[4], al[4];
#pragma unroll
        for (int mt = 0; mt < 4; ++mt) {
            ah[mt] = *(const bf16x8*)&Ah[wy * 4 + mt][l][0];
            al[mt] = *(const bf16x8*)&Al[wy * 4 + mt][l][0];
        }
#pragma unroll
        for (int nt = 0; nt < 4; ++nt) {
            bf16x8 bh = *(const bf16x8*)&Bh[wx * 4 + nt][l][0];
            bf16x8 bl = *(const bf16x8*)&Bl[wx * 4 + nt][l][0];
#pragma unroll
            for (int mt = 0; mt < 4; ++mt) {
                acc[mt][nt] = __builtin_amdgcn_mfma_f32_16x16x32_bf16(ah[mt], bh, acc[mt][nt], 0, 0, 0);
                acc[mt][nt] = __builtin_amdgcn_mfma_f32_16x16x32_bf16(al[mt], bl, acc[mt][nt], 0, 0, 0);
                acc[mt][nt] = __builtin_amdgcn_mfma_f32_16x16x32_bf16(ah[mt], bl, acc[mt][nt], 0, 0, 0);
                acc[mt][nt] = __builtin_amdgcn_mfma_f32_16x16x32_bf16(al[mt], bh, acc[mt][nt], 0, 0, 0);
            }
        }
    }

    // epilogue: scale by rk, per-row argmax over this block's 128 cols
    const int q = l >> 4, c = l & 15;
    float rk_l[4];
#pragma unroll
    for (int nt = 0; nt < 4; ++nt) rk_l[nt] = RK[cwBase + wx * 64 + nt * 16 + c];
#pragma unroll
    for (int mt = 0; mt < 4; ++mt) {
#pragma unroll
        for (int r = 0; r < 4; ++r) {
            float best = -INFINITY;
            int bcol = 0x7fffffff;
#pragma unroll
            for (int nt = 0; nt < 4; ++nt) {
                float v = acc[mt][nt][r] * rk_l[nt];
                int col = cwBase + wx * 64 + nt * 16 + c;
                if (v > best || (v == best && col < bcol)) { best = v; bcol = col; }
            }
            // packed u64: (sortable value key << 32) | ~idx  -> plain u64 max == (max val, min idx)
            unsigned long long pk = ((unsigned long long)sortable_key(best) << 32) |
                                    (unsigned long long)(~(unsigned int)bcol);
#pragma unroll
            for (int m = 1; m < 16; m <<= 1) {
                unsigned long long o = __shfl_xor(pk, m, 64);
                if (o > pk) pk = o;
            }
            if (c == 0) red[wy * 64 + mt * 16 + q * 4 + r][wx] = pk;
        }
    }
    __syncthreads();
    if (tid < 128) {
        unsigned long long a = red[tid][0], b = red[tid][1];
        if (b > a) a = b;
        atomicMax(packed + (rowBase + tid), a);
    }
}

// ---------------- unpack argmax results (apply deferred rq to word_sim) ----------------
__global__ __launch_bounds__(256) void finalize_kernel(const unsigned long long* __restrict__ packed,
                                                       const float* __restrict__ RQ,
                                                       float* __restrict__ outIdx,
                                                       float* __restrict__ outSim,
                                                       int* __restrict__ idxArr) {
    int row = blockIdx.x * 256 + threadIdx.x;
    if (row >= NROWS) return;
    unsigned long long p = packed[row];
    unsigned int key = (unsigned int)(p >> 32);
    unsigned int b = (key & 0x80000000u) ? (key & 0x7FFFFFFFu) : ~key;
    int idx = (int)(~(unsigned int)(p & 0xFFFFFFFFull));
    outIdx[row] = (float)idx;
    outSim[row] = __uint_as_float(b) * RQ[row];
    idxArr[row] = idx;
}

// ---------------- per-row LN stats (mean, rstd) of e = (z-x)+x ----------------
__global__ __launch_bounds__(256) void ln_stats_kernel(const float* __restrict__ X,
                                                       const float* __restrict__ W,
                                                       const int* __restrict__ idxArr,
                                                       float* __restrict__ MU,
                                                       float* __restrict__ RS) {
    __shared__ float red[8];
    int row = blockIdx.x;
    int tid = threadIdx.x;
    int idx = idxArr[row];
    float4 z  = *((const float4*)(W + (size_t)idx * D) + tid);
    float4 xv = *((const float4*)(X + (size_t)row * D) + tid);
    float4 e;
    e.x = (z.x - xv.x) + xv.x;
    e.y = (z.y - xv.y) + xv.y;
    e.z = (z.z - xv.z) + xv.z;
    e.w = (z.w - xv.w) + xv.w;
    float s  = e.x + e.y + e.z + e.w;
    float s2 = e.x * e.x + e.y * e.y + e.z * e.z + e.w * e.w;
#pragma unroll
    for (int m = 32; m >= 1; m >>= 1) {
        s  += __shfl_xor(s, m, 64);
        s2 += __shfl_xor(s2, m, 64);
    }
    int wave = tid >> 6, lane = tid & 63;
    if (lane == 0) { red[wave] = s; red[4 + wave] = s2; }
    __syncthreads();
    if (tid == 0) {
        s  = red[0] + red[1] + red[2] + red[3];
        s2 = red[4] + red[5] + red[6] + red[7];
        float mean = s * (1.f / D);
        float var  = s2 * (1.f / D) - mean * mean;
        MU[row] = mean;
        RS[row] = rsqrtf(var + 1e-6f);
    }
}

// ---------------- projection GEMM with fused gather+STE+LN on A-staging ----------------
__global__ __launch_bounds__(256) void gemm2_kernel(const float* __restrict__ X,
                                                    const float* __restrict__ W,
                                                    const int* __restrict__ idxArr,
                                                    const float* __restrict__ MU,
                                                    const float* __restrict__ RS,
                                                    const float* __restrict__ gamma,
                                                    const float* __restrict__ beta,
                                                    const float* __restrict__ B,
                                                    float* __restrict__ Out) {
    const int AP = 132;
    __shared__ __align__(16) float As[16 * AP];
    __shared__ __align__(16) float Bs[16 * AP];
    int tid = threadIdx.x;
    int tx = tid & 15, ty = tid >> 4;
    int rowBase = blockIdx.y * 128;
    int nBase   = blockIdx.x * 128;
    float acc[8][8];
#pragma unroll
    for (int r = 0; r < 8; ++r)
#pragma unroll
        for (int c = 0; c < 8; ++c) acc[r][c] = 0.f;

    for (int kc = 0; kc < D; kc += 16) {
#pragma unroll
        for (int i = 0; i < 2; ++i) {
            int f = tid + i * 256;
            int row = f >> 2;
            int d4 = (f & 3) * 4;
            int grow = rowBase + row;
            int col = kc + d4;
            int idx = idxArr[grow];
            float4 z  = *(const float4*)(W + (size_t)idx * D + col);
            float4 xv = *(const float4*)(X + (size_t)grow * D + col);
            float4 g  = *(const float4*)(gamma + col);
            float4 bb = *(const float4*)(beta + col);
            float mu_ = MU[grow];
            float rs_ = RS[grow];
            float4 a;
            a.x = (((z.x - xv.x) + xv.x) - mu_) * rs_ * g.x + bb.x;
            a.y = (((z.y - xv.y) + xv.y) - mu_) * rs_ * g.y + bb.y;
            a.z = (((z.z - xv.z) + xv.z) - mu_) * rs_ * g.z + bb.z;
            a.w = (((z.w - xv.w) + xv.w) - mu_) * rs_ * g.w + bb.w;
            As[(d4 + 0) * AP + row] = a.x;
            As[(d4 + 1) * AP + row] = a.y;
            As[(d4 + 2) * AP + row] = a.z;
            As[(d4 + 3) * AP + row] = a.w;
            int n4 = (f & 31) * 4;
            int d  = f >> 5;
            float4 b = *(const float4*)(B + (size_t)(kc + d) * D + nBase + n4);
            *(float4*)(Bs + d * AP + n4) = b;
        }
        __syncthreads();
#pragma unroll
        for (int d = 0; d < 16; ++d) {
            float4 a0 = *(const float4*)(As + d * AP + ty * 4);
            float4 a1 = *(const float4*)(As + d * AP + 64 + ty * 4);
            float4 b0 = *(const float4*)(Bs + d * AP + tx * 4);
            float4 b1 = *(const float4*)(Bs + d * AP + 64 + tx * 4);
            float ar[8] = {a0.x, a0.y, a0.z, a0.w, a1.x, a1.y, a1.z, a1.w};
            float br[8] = {b0.x, b0.y, b0.z, b0.w, b1.x, b1.y, b1.z, b1.w};
#pragma unroll
            for (int r = 0; r < 8; ++r)
#pragma unroll
                for (int c = 0; c < 8; ++c)
                    acc[r][c] = fmaf(ar[r], br[c], acc[r][c]);
        }
        __syncthreads();
    }
#pragma unroll
    for (int r = 0; r < 8; ++r) {
        int lrow = (r < 4) ? (ty * 4 + r) : (64 + ty * 4 + r - 4);
        float4 o0 = {acc[r][0], acc[r][1], acc[r][2], acc[r][3]};
        float4 o1 = {acc[r][4], acc[r][5], acc[r][6], acc[r][7]};
        *(float4*)(Out + (size_t)(rowBase + lrow) * D + nBase + tx * 4) = o0;
        *(float4*)(Out + (size_t)(rowBase + lrow) * D + nBase + 64 + tx * 4) = o1;
    }
}

extern "C" void kernel_launch(void* const* d_in, const int* in_sizes, int n_in,
                              void* d_out, int out_size, void* d_ws, size_t ws_size,
                              hipStream_t stream) {
    const float* X     = (const float*)d_in[0];  // [8192,1024]
    const float* W     = (const float*)d_in[1];  // [16384,1024]
    const float* gamma = (const float*)d_in[2];  // [1024]
    const float* beta  = (const float*)d_in[3];  // [1024]
    const float* OW    = (const float*)d_in[4];  // [1024,1024]

    float* out    = (float*)d_out;
    float* outIdx = out;               // word_idx as float values
    float* outSim = out + NROWS;       // word_sim
    float* outO   = out + 2 * NROWS;   // projection output

    // workspace layout — 256 KB total
    unsigned long long* packed = (unsigned long long*)d_ws;  // 8192 u64
    float* RK     = (float*)(packed + NROWS);                // 16384 f
    float* RQ     = RK + V;                                  // 8192 f
    float* MU     = RQ + NROWS;                              // 8192 f
    float* RS     = MU + NROWS;                              // 8192 f
    int*   idxArr = (int*)(RS + NROWS);                      // 8192 i

    hipLaunchKernelGGL(rownorm_kernel, dim3(V / 4), dim3(256), 0, stream, W, RK, V);
    hipLaunchKernelGGL(rownorm_kernel, dim3(NROWS / 4), dim3(256), 0, stream, X, RQ, NROWS);
    hipLaunchKernelGGL(zero_kernel, dim3(NROWS / 256), dim3(256), 0, stream, packed, NROWS);
    hipLaunchKernelGGL(gemm1_kernel, dim3(128, 64), dim3(256), 0, stream, X, W, RK, packed);
    hipLaunchKernelGGL(finalize_kernel, dim3(NROWS / 256), dim3(256), 0, stream, packed, RQ, outIdx, outSim, idxArr);
    hipLaunchKernelGGL(ln_stats_kernel, dim3(NROWS), dim3(256), 0, stream, X, W, idxArr, MU, RS);
    hipLaunchKernelGGL(gemm2_kernel, dim3(8, 64), dim3(256), 0, stream, X, W, idxArr, MU, RS, gamma, beta, OW, outO);
}

// Round 4
// 1003.620 us; speedup vs baseline: 3.3146x; 1.2678x over previous
//
#include <hip/hip_runtime.h>
#include <math.h>

#define D 1024
#define V 16384
#define NROWS 8192

typedef __bf16 bf16_t;
typedef bf16_t bf16x8 __attribute__((ext_vector_type(8)));
typedef float f32x4 __attribute__((ext_vector_type(4)));

__device__ __forceinline__ unsigned int sortable_key(float v) {
    unsigned int b = __float_as_uint(v);
    return (b & 0x80000000u) ? ~b : (b | 0x80000000u);
}

// split float4 -> bf16 hi (truncate) + bf16 lo (truncate of x - hi)
__device__ __forceinline__ void split4(float4 v, uint2& hw, uint2& lw) {
    unsigned int u0 = __float_as_uint(v.x), u1 = __float_as_uint(v.y);
    unsigned int u2 = __float_as_uint(v.z), u3 = __float_as_uint(v.w);
    float l0 = v.x - __uint_as_float(u0 & 0xFFFF0000u);
    float l1 = v.y - __uint_as_float(u1 & 0xFFFF0000u);
    float l2 = v.z - __uint_as_float(u2 & 0xFFFF0000u);
    float l3 = v.w - __uint_as_float(u3 & 0xFFFF0000u);
    hw.x = (u0 >> 16) | (u1 & 0xFFFF0000u);
    hw.y = (u2 >> 16) | (u3 & 0xFFFF0000u);
    lw.x = (__float_as_uint(l0) >> 16) | (__float_as_uint(l1) & 0xFFFF0000u);
    lw.y = (__float_as_uint(l2) >> 16) | (__float_as_uint(l3) & 0xFFFF0000u);
}

// ---------------- row L2-norm ----------------
__global__ __launch_bounds__(256) void rownorm_kernel(const float* __restrict__ M,
                                                      float* __restrict__ R, int nrows) {
    int tid = threadIdx.x;
    int row = blockIdx.x * 4 + (tid >> 6);
    int lane = tid & 63;
    if (row >= nrows) return;
    const float4* p = (const float4*)(M + (size_t)row * D);
    float ss = 0.f;
#pragma unroll
    for (int i = 0; i < 4; ++i) {
        float4 v = p[lane + 64 * i];
        ss += v.x * v.x + v.y * v.y + v.z * v.z + v.w * v.w;
    }
#pragma unroll
    for (int m = 32; m >= 1; m >>= 1) ss += __shfl_xor(ss, m, 64);
    if (lane == 0) R[row] = rsqrtf(fmaxf(ss, 1e-12f));
}

__global__ __launch_bounds__(256) void zero_kernel(unsigned long long* __restrict__ p, int n) {
    int i = blockIdx.x * 256 + threadIdx.x;
    if (i < n) p[i] = 0ull;
}

// ---------------- pre-split X into fragment-packed bf16 hi/lo ----------------
// layout: Xhi[((t16*32 + kc)*64 + lane)*8 + j], t16=row>>4, lane=(row&15)|((kk>>3)<<4), j=kk&7
__global__ __launch_bounds__(256) void xsplit_kernel(const float* __restrict__ X,
                                                     ushort* __restrict__ Xhi,
                                                     ushort* __restrict__ Xlo) {
    int f = blockIdx.x * 256 + threadIdx.x;   // 0 .. NROWS*D/4
    int row = f >> 8;
    int kq = f & 255;
    int k0 = kq * 4;
    float4 v = *((const float4*)(X + (size_t)row * D) + kq);
    uint2 hw, lw;
    split4(v, hw, lw);
    int t16 = row >> 4, m = row & 15;
    int kc = k0 >> 5, kk = k0 & 31;
    int lane = m | ((kk >> 3) << 4);
    int j0 = kk & 4;
    int idx = ((t16 * 32 + kc) * 64 + lane) * 8 + j0;
    *(uint2*)(Xhi + idx) = hw;
    *(uint2*)(Xlo + idx) = lw;
}

// ---------------- sim GEMM: bf16 3-pass (hh+hl+lh) MFMA + fused argmax ----------------
// tile: 128 rows x 256 cols; A-frags direct from pre-split global; B split in-kernel -> LDS
__global__ __launch_bounds__(256, 2) void gemm1_kernel(const ushort* __restrict__ Xhi,
                                                       const ushort* __restrict__ Xlo,
                                                       const float* __restrict__ W,
                                                       const float* __restrict__ RK,
                                                       unsigned long long* __restrict__ packed) {
    __shared__ ushort Bh[16][64][8];
    __shared__ ushort Bl[16][64][8];
    __shared__ unsigned long long red[128][2];

    const int tid = threadIdx.x;
    const int l = tid & 63;
    const int wave = tid >> 6;
    const int wy = wave >> 1, wx = wave & 1;   // wave tile: 64 rows x 128 cols
    const int rowBase = blockIdx.y * 128;
    const int cwBase  = blockIdx.x * 256;

    f32x4 acc[4][8];
#pragma unroll
    for (int mt = 0; mt < 4; ++mt)
#pragma unroll
        for (int nt = 0; nt < 8; ++nt) acc[mt][nt] = (f32x4)0.f;

    const float4* Wb = (const float4*)(W + (size_t)cwBase * D);

    float4 pb[8];
#pragma unroll
    for (int i = 0; i < 8; ++i) {
        int f = i * 256 + tid;
        int row = f >> 3, kq = f & 7;
        pb[i] = Wb[row * (D / 4) + kq];
    }

    const int t16base = blockIdx.y * 8 + wy * 4;

    for (int kc = 0; kc < 32; ++kc) {
        __syncthreads();
        // A-frag global loads (independent of LDS) — issue early, latency hides behind B split
        bf16x8 ah[4], al[4];
#pragma unroll
        for (int mt = 0; mt < 4; ++mt) {
            int off = (((t16base + mt) * 32 + kc) * 64 + l) * 8;
            ah[mt] = *(const bf16x8*)(Xhi + off);
            al[mt] = *(const bf16x8*)(Xlo + off);
        }
        // B split + stage
#pragma unroll
        for (int i = 0; i < 8; ++i) {
            int f = i * 256 + tid;
            int row = f >> 3, kq = f & 7;
            int tile = row >> 4;
            int lf = (row & 15) | ((kq >> 1) << 4);
            int j0 = (kq & 1) * 4;
            uint2 hw, lw;
            split4(pb[i], hw, lw);
            *(uint2*)&Bh[tile][lf][j0] = hw;
            *(uint2*)&Bl[tile][lf][j0] = lw;
        }
        __syncthreads();
        if (kc < 31) {
#pragma unroll
            for (int i = 0; i < 8; ++i) {
                int f = i * 256 + tid;
                int row = f >> 3, kq = f & 7;
                pb[i] = Wb[row * (D / 4) + (kc + 1) * 8 + kq];
            }
        }
#pragma unroll
        for (int nt = 0; nt < 8; ++nt) {
            bf16x8 bh = *(const bf16x8*)&Bh[wx * 8 + nt][l][0];
            bf16x8 bl = *(const bf16x8*)&Bl[wx * 8 + nt][l][0];
#pragma unroll
            for (int mt = 0; mt < 4; ++mt) {
                acc[mt][nt] = __builtin_amdgcn_mfma_f32_16x16x32_bf16(ah[mt], bh, acc[mt][nt], 0, 0, 0);
                acc[mt][nt] = __builtin_amdgcn_mfma_f32_16x16x32_bf16(ah[mt], bl, acc[mt][nt], 0, 0, 0);
                acc[mt][nt] = __builtin_amdgcn_mfma_f32_16x16x32_bf16(al[mt], bh, acc[mt][nt], 0, 0, 0);
            }
        }
    }

    // epilogue: scale by rk, per-row argmax over this block's 256 cols
    const int q = l >> 4, c = l & 15;
    float rk_l[8];
#pragma unroll
    for (int nt = 0; nt < 8; ++nt) rk_l[nt] = RK[cwBase + wx * 128 + nt * 16 + c];
#pragma unroll
    for (int mt = 0; mt < 4; ++mt) {
#pragma unroll
        for (int r = 0; r < 4; ++r) {
            float best = -INFINITY;
            int bcol = 0x7fffffff;
#pragma unroll
            for (int nt = 0; nt < 8; ++nt) {
                float v = acc[mt][nt][r] * rk_l[nt];
                int col = cwBase + wx * 128 + nt * 16 + c;
                if (v > best || (v == best && col < bcol)) { best = v; bcol = col; }
            }
            unsigned long long pk = ((unsigned long long)sortable_key(best) << 32) |
                                    (unsigned long long)(~(unsigned int)bcol);
#pragma unroll
            for (int m = 1; m < 16; m <<= 1) {
                unsigned long long o = __shfl_xor(pk, m, 64);
                if (o > pk) pk = o;
            }
            if (c == 0) red[wy * 64 + mt * 16 + q * 4 + r][wx] = pk;
        }
    }
    __syncthreads();
    if (tid < 128) {
        unsigned long long a = red[tid][0], b = red[tid][1];
        if (b > a) a = b;
        atomicMax(packed + (rowBase + tid), a);
    }
}

// ---------------- unpack argmax results ----------------
__global__ __launch_bounds__(256) void finalize_kernel(const unsigned long long* __restrict__ packed,
                                                       const float* __restrict__ RQ,
                                                       float* __restrict__ outIdx,
                                                       float* __restrict__ outSim,
                                                       int* __restrict__ idxArr) {
    int row = blockIdx.x * 256 + threadIdx.x;
    if (row >= NROWS) return;
    unsigned long long p = packed[row];
    unsigned int key = (unsigned int)(p >> 32);
    unsigned int b = (key & 0x80000000u) ? (key & 0x7FFFFFFFu) : ~key;
    int idx = (int)(~(unsigned int)(p & 0xFFFFFFFFull));
    outIdx[row] = (float)idx;
    outSim[row] = __uint_as_float(b) * RQ[row];
    idxArr[row] = idx;
}

// ---------------- per-row LN stats ----------------
__global__ __launch_bounds__(256) void ln_stats_kernel(const float* __restrict__ X,
                                                       const float* __restrict__ W,
                                                       const int* __restrict__ idxArr,
                                                       float* __restrict__ MU,
                                                       float* __restrict__ RS) {
    __shared__ float red[8];
    int row = blockIdx.x;
    int tid = threadIdx.x;
    int idx = idxArr[row];
    float4 z  = *((const float4*)(W + (size_t)idx * D) + tid);
    float4 xv = *((const float4*)(X + (size_t)row * D) + tid);
    float4 e;
    e.x = (z.x - xv.x) + xv.x;
    e.y = (z.y - xv.y) + xv.y;
    e.z = (z.z - xv.z) + xv.z;
    e.w = (z.w - xv.w) + xv.w;
    float s  = e.x + e.y + e.z + e.w;
    float s2 = e.x * e.x + e.y * e.y + e.z * e.z + e.w * e.w;
#pragma unroll
    for (int m = 32; m >= 1; m >>= 1) {
        s  += __shfl_xor(s, m, 64);
        s2 += __shfl_xor(s2, m, 64);
    }
    int wave = tid >> 6, lane = tid & 63;
    if (lane == 0) { red[wave] = s; red[4 + wave] = s2; }
    __syncthreads();
    if (tid == 0) {
        s  = red[0] + red[1] + red[2] + red[3];
        s2 = red[4] + red[5] + red[6] + red[7];
        float mean = s * (1.f / D);
        float var  = s2 * (1.f / D) - mean * mean;
        MU[row] = mean;
        RS[row] = rsqrtf(var + 1e-6f);
    }
}

// ---------------- projection GEMM: bf16 3-pass MFMA, LN fused into A staging ----------------
__global__ __launch_bounds__(256, 2) void gemm2_kernel(const float* __restrict__ X,
                                                       const float* __restrict__ W,
                                                       const int* __restrict__ idxArr,
                                                       const float* __restrict__ MU,
                                                       const float* __restrict__ RS,
                                                       const float* __restrict__ gamma,
                                                       const float* __restrict__ beta,
                                                       const float* __restrict__ B,
                                                       float* __restrict__ Out) {
    __shared__ ushort Ah[8][64][8];
    __shared__ ushort Al[8][64][8];
    __shared__ ushort Bh[8][64][8];
    __shared__ ushort Bl[8][64][8];

    const int tid = threadIdx.x;
    const int l = tid & 63;
    const int wave = tid >> 6;
    const int wy = wave >> 1, wx = wave & 1;   // wave tile: 64 rows x 64 cols
    const int rowBase = blockIdx.y * 128;
    const int nBase   = blockIdx.x * 128;

    f32x4 acc[4][4];
#pragma unroll
    for (int mt = 0; mt < 4; ++mt)
#pragma unroll
        for (int nt = 0; nt < 4; ++nt) acc[mt][nt] = (f32x4)0.f;

    // hoist per-row LN params for the 4 A rows this thread stages
    int arow[4], aidx[4];
    float amu[4], ars[4];
#pragma unroll
    for (int i = 0; i < 4; ++i) {
        int f = i * 256 + tid;
        arow[i] = f >> 3;
        int grow = rowBase + arow[i];
        aidx[i] = idxArr[grow];
        amu[i] = MU[grow];
        ars[i] = RS[grow];
    }

    for (int kc = 0; kc < 32; ++kc) {
        __syncthreads();
        // A staging: gather + STE + LN + split
#pragma unroll
        for (int i = 0; i < 4; ++i) {
            int f = i * 256 + tid;
            int row = arow[i], kq = f & 7;
            int col = kc * 32 + kq * 4;
            float4 z  = *(const float4*)(W + (size_t)aidx[i] * D + col);
            float4 xv = *(const float4*)(X + (size_t)(rowBase + row) * D + col);
            float4 g  = *(const float4*)(gamma + col);
            float4 bb = *(const float4*)(beta + col);
            float4 a;
            a.x = (((z.x - xv.x) + xv.x) - amu[i]) * ars[i] * g.x + bb.x;
            a.y = (((z.y - xv.y) + xv.y) - amu[i]) * ars[i] * g.y + bb.y;
            a.z = (((z.z - xv.z) + xv.z) - amu[i]) * ars[i] * g.z + bb.z;
            a.w = (((z.w - xv.w) + xv.w) - amu[i]) * ars[i] * g.w + bb.w;
            uint2 hw, lw;
            split4(a, hw, lw);
            int tile = row >> 4;
            int lf = (row & 15) | ((kq >> 1) << 4);
            int j0 = (kq & 1) * 4;
            *(uint2*)&Ah[tile][lf][j0] = hw;
            *(uint2*)&Al[tile][lf][j0] = lw;
        }
        // B staging: each thread loads 4 k-strided elements of one column n
#pragma unroll
        for (int i = 0; i < 4; ++i) {
            int f = i * 256 + tid;
            int n = f & 127, dq = f >> 7;
            const float* bp = B + (size_t)(kc * 32 + dq * 4) * D + nBase + n;
            float b0 = bp[0], b1 = bp[D], b2 = bp[2 * D], b3 = bp[3 * D];
            float4 v = {b0, b1, b2, b3};
            uint2 hw, lw;
            split4(v, hw, lw);
            int tile = n >> 4;
            int lf = (n & 15) | ((dq >> 1) << 4);
            int j0 = (dq & 1) * 4;
            *(uint2*)&Bh[tile][lf][j0] = hw;
            *(uint2*)&Bl[tile][lf][j0] = lw;
        }
        __syncthreads();
        bf16x8 ah[4], al[4];
#pragma unroll
        for (int mt = 0; mt < 4; ++mt) {
            ah[mt] = *(const bf16x8*)&Ah[wy * 4 + mt][l][0];
            al[mt] = *(const bf16x8*)&Al[wy * 4 + mt][l][0];
        }
#pragma unroll
        for (int nt = 0; nt < 4; ++nt) {
            bf16x8 bh = *(const bf16x8*)&Bh[wx * 4 + nt][l][0];
            bf16x8 bl = *(const bf16x8*)&Bl[wx * 4 + nt][l][0];
#pragma unroll
            for (int mt = 0; mt < 4; ++mt) {
                acc[mt][nt] = __builtin_amdgcn_mfma_f32_16x16x32_bf16(ah[mt], bh, acc[mt][nt], 0, 0, 0);
                acc[mt][nt] = __builtin_amdgcn_mfma_f32_16x16x32_bf16(ah[mt], bl, acc[mt][nt], 0, 0, 0);
                acc[mt][nt] = __builtin_amdgcn_mfma_f32_16x16x32_bf16(al[mt], bh, acc[mt][nt], 0, 0, 0);
            }
        }
    }

    const int q = l >> 4, c = l & 15;
#pragma unroll
    for (int mt = 0; mt < 4; ++mt)
#pragma unroll
        for (int nt = 0; nt < 4; ++nt)
#pragma unroll
            for (int r = 0; r < 4; ++r) {
                int grow = rowBase + wy * 64 + mt * 16 + q * 4 + r;
                int gcol = nBase + wx * 64 + nt * 16 + c;
                Out[(size_t)grow * D + gcol] = acc[mt][nt][r];
            }
}

extern "C" void kernel_launch(void* const* d_in, const int* in_sizes, int n_in,
                              void* d_out, int out_size, void* d_ws, size_t ws_size,
                              hipStream_t stream) {
    const float* X     = (const float*)d_in[0];
    const float* W     = (const float*)d_in[1];
    const float* gamma = (const float*)d_in[2];
    const float* beta  = (const float*)d_in[3];
    const float* OW    = (const float*)d_in[4];

    float* out    = (float*)d_out;
    float* outIdx = out;
    float* outSim = out + NROWS;
    float* outO   = out + 2 * NROWS;

    // Xsplit scratch lives in the outO region (exactly 32 MB; overwritten by gemm2 at the end)
    ushort* Xhi = (ushort*)outO;
    ushort* Xlo = Xhi + (size_t)NROWS * D;

    // workspace — 256 KB
    unsigned long long* packed = (unsigned long long*)d_ws;
    float* RK     = (float*)(packed + NROWS);
    float* RQ     = RK + V;
    float* MU     = RQ + NROWS;
    float* RS     = MU + NROWS;
    int*   idxArr = (int*)(RS + NROWS);

    hipLaunchKernelGGL(rownorm_kernel, dim3(V / 4), dim3(256), 0, stream, W, RK, V);
    hipLaunchKernelGGL(rownorm_kernel, dim3(NROWS / 4), dim3(256), 0, stream, X, RQ, NROWS);
    hipLaunchKernelGGL(zero_kernel, dim3(NROWS / 256), dim3(256), 0, stream, packed, NROWS);
    hipLaunchKernelGGL(xsplit_kernel, dim3(NROWS * (D / 4) / 256), dim3(256), 0, stream, X, Xhi, Xlo);
    hipLaunchKernelGGL(gemm1_kernel, dim3(V / 256, NROWS / 128), dim3(256), 0, stream, Xhi, Xlo, W, RK, packed);
    hipLaunchKernelGGL(finalize_kernel, dim3(NROWS / 256), dim3(256), 0, stream, packed, RQ, outIdx, outSim, idxArr);
    hipLaunchKernelGGL(ln_stats_kernel, dim3(NROWS), dim3(256), 0, stream, X, W, idxArr, MU, RS);
    hipLaunchKernelGGL(gemm2_kernel, dim3(D / 128, NROWS / 128), dim3(256), 0, stream,
                       X, W, idxArr, MU, RS, gamma, beta, OW, outO);
}